// Round 1
// baseline (755.579 us; speedup 1.0000x reference)
//
#include <hip/hip_runtime.h>

// Problem constants
#define SEQ   512
#define BATCH 4
#define NN    128
#define HID   64
#define G4    256   // 4*HID gates per layer

__device__ __forceinline__ float sigm(float x)   { return 1.f / (1.f + expf(-x)); }
__device__ __forceinline__ float tanh_e(float x) { return 2.f / (1.f + expf(-2.f * x)) - 1.f; }
__device__ __forceinline__ float lrelu(float x)  { return x > 0.f ? x : 0.2f * x; }

// ---------------------------------------------------------------------------
// Kernel A: X0[t][b][g] = bih0[g]+bhh0[g] + sum_k x[b,t,k] * Wih0[g,k]
// Time-parallel input GEMM for LSTM layer 0. Grid 128 x 256 threads,
// each block does 16 (t,b) rows; Wih0 row held in 128 VGPRs per thread.
// ---------------------------------------------------------------------------
__global__ __launch_bounds__(256) void x0_gemm(
    const float* __restrict__ x, const float* __restrict__ Wih0,
    const float* __restrict__ bih0, const float* __restrict__ bhh0,
    float* __restrict__ X0)
{
  const int g = threadIdx.x;
  float w[128];
  {
    const float4* wp = reinterpret_cast<const float4*>(Wih0 + g * 128);
#pragma unroll
    for (int i = 0; i < 32; ++i) {
      float4 t = wp[i];
      w[4*i] = t.x; w[4*i+1] = t.y; w[4*i+2] = t.z; w[4*i+3] = t.w;
    }
  }
  const float bsum = bih0[g] + bhh0[g];
  __shared__ __align__(16) float xls[NN];
  const int r0 = blockIdx.x * 16;
  for (int r = r0; r < r0 + 16; ++r) {
    const int tt = r >> 2, b = r & 3;
    if (g < NN) xls[g] = x[(b * SEQ + tt) * NN + g];
    __syncthreads();
    float acc = bsum;
#pragma unroll
    for (int k = 0; k < 128; k += 4) {
      float4 h4 = *reinterpret_cast<const float4*>(&xls[k]);
      acc += w[k] * h4.x + w[k+1] * h4.y + w[k+2] * h4.z + w[k+3] * h4.w;
    }
    X0[r * G4 + g] = acc;
    __syncthreads();
  }
}

// ---------------------------------------------------------------------------
// Kernel B: fused 2-layer LSTM scan. Grid = 4 blocks (one per batch),
// 512 threads: [0,256) = layer0 gates, [256,512) = layer1 gates.
// Layer1 is skewed one step behind layer0 (software pipeline), so the
// per-iteration critical path is one layer, not two. Weights in VGPRs,
// h-state broadcast via LDS (same-address float4 reads -> free broadcast).
// ---------------------------------------------------------------------------
__global__ __launch_bounds__(512, 2) void lstm_scan(
    const float* __restrict__ X0,
    const float* __restrict__ Whh0,
    const float* __restrict__ Wih1, const float* __restrict__ Whh1,
    const float* __restrict__ bih1, const float* __restrict__ bhh1,
    float* __restrict__ xl_out)
{
  const int b = blockIdx.x;
  const int tid = threadIdx.x;
  const int group = tid >> 8;   // 0 = layer0, 1 = layer1
  const int g = tid & 255;
  const int type = g >> 6;      // 0:i 1:f 2:g 3:o (PyTorch order)

  __shared__ __align__(16) float h0s[HID];
  __shared__ __align__(16) float h1s[HID];
  __shared__ float gact[2][G4];

  float wa[64], wb[64];
  float bsum = 0.f;
  if (group == 0) {
    const float4* p = reinterpret_cast<const float4*>(Whh0 + g * 64);
#pragma unroll
    for (int i = 0; i < 16; ++i) {
      float4 t = p[i];
      wa[4*i] = t.x; wa[4*i+1] = t.y; wa[4*i+2] = t.z; wa[4*i+3] = t.w;
    }
  } else {
    const float4* p = reinterpret_cast<const float4*>(Wih1 + g * 64);
    const float4* q = reinterpret_cast<const float4*>(Whh1 + g * 64);
#pragma unroll
    for (int i = 0; i < 16; ++i) {
      float4 t = p[i];
      wa[4*i] = t.x; wa[4*i+1] = t.y; wa[4*i+2] = t.z; wa[4*i+3] = t.w;
      float4 u2 = q[i];
      wb[4*i] = u2.x; wb[4*i+1] = u2.y; wb[4*i+2] = u2.z; wb[4*i+3] = u2.w;
    }
    bsum = bih1[g] + bhh1[g];
  }
  if (tid < HID) h0s[tid] = 0.f;
  else if (tid >= 256 && tid < 256 + HID) h1s[tid - 256] = 0.f;

  float cst = 0.f;               // cell state, owned by combine threads (g<64)
  float cur = 0.f, nxt = 0.f;    // X0 prefetch pipeline (layer0 only)
  if (group == 0) cur = X0[b * G4 + g];
  __syncthreads();

  for (int tt = 0; tt <= SEQ; ++tt) {
    const bool active = (group == 0) ? (tt < SEQ) : (tt >= 1);
    float acc = 0.f;
    if (group == 0) {
      if (tt < SEQ) {
        const int nt = (tt + 1 < SEQ) ? (tt + 1) : (SEQ - 1);
        nxt = X0[(nt * BATCH + b) * G4 + g];   // prefetch next step
        acc = cur;
#pragma unroll
        for (int k = 0; k < HID; k += 4) {
          float4 h4 = *reinterpret_cast<const float4*>(&h0s[k]);
          acc += wa[k] * h4.x + wa[k+1] * h4.y + wa[k+2] * h4.z + wa[k+3] * h4.w;
        }
      }
    } else {
      if (tt >= 1) {
        acc = bsum;
#pragma unroll
        for (int k = 0; k < HID; k += 4) {
          float4 h4 = *reinterpret_cast<const float4*>(&h0s[k]);   // = h0[tt-1]
          float4 g4 = *reinterpret_cast<const float4*>(&h1s[k]);   // = h1[tt-2]
          acc += wa[k] * h4.x + wa[k+1] * h4.y + wa[k+2] * h4.z + wa[k+3] * h4.w;
          acc += wb[k] * g4.x + wb[k+1] * g4.y + wb[k+2] * g4.z + wb[k+3] * g4.w;
        }
      }
    }
    const float act = (type == 2) ? tanh_e(acc) : sigm(acc);
    if (active) gact[group][g] = act;
    __syncthreads();
    if (active && g < HID) {
      const float i_ = gact[group][g];
      const float f_ = gact[group][HID + g];
      const float gg = gact[group][2 * HID + g];
      const float o_ = gact[group][3 * HID + g];
      cst = f_ * cst + i_ * gg;
      const float h = o_ * tanh_e(cst);
      if (group == 0) h0s[g] = h; else h1s[g] = h;
    }
    if (group == 0) cur = nxt;
    __syncthreads();
  }
  if (group == 1 && g < HID) xl_out[b * HID + g] = h1s[g];
}

// ---------------------------------------------------------------------------
// Kernel C: GAT for the 4 last-timestep graphs only (output only uses s=S-1).
// GAT1 is rank-1 (Wh = x*u + v) so attn@Wh collapses to p[i]*u[f]+v[f] with
// p[i] = sum_j attn[i,j]*x[j]. GAT2 done explicitly on the 128x8 Wh2.
// adjm staged in LDS with pitch 129 (bank-conflict-free row access).
// ---------------------------------------------------------------------------
__global__ __launch_bounds__(256) void gat_kernel(
    const float* __restrict__ x, const int* __restrict__ adj,
    const float* __restrict__ emb_w, const float* __restrict__ emb_b,
    const float* __restrict__ W1, const float* __restrict__ a1,
    const float* __restrict__ W2, const float* __restrict__ a2,
    float* __restrict__ xg_out)
{
  const int b = blockIdx.x;
  const int tid = threadIdx.x;
  __shared__ float adjm[NN * 129];
  __shared__ __align__(16) float xls[NN];
  __shared__ float u[16], v[16];
  __shared__ float Wh2[NN][9];
  __shared__ float f1b[NN], f2b[NN];
  __shared__ float p[NN];

  for (int idx = tid; idx < NN * NN; idx += 256)
    adjm[(idx >> 7) * 129 + (idx & 127)] = (adj[idx] > 0) ? 1.f : 0.f;
  if (tid < NN) xls[tid] = x[(b * SEQ + (SEQ - 1)) * NN + tid];
  if (tid < 16) {
    float uu = 0.f, vv = 0.f;
    for (int fp = 0; fp < 16; ++fp) {
      uu += emb_w[fp] * W1[fp * 16 + tid];
      vv += emb_b[fp] * W1[fp * 16 + tid];
    }
    u[tid] = uu; v[tid] = vv;
  }
  __syncthreads();
  float s1 = 0.f, t1 = 0.f, s2 = 0.f, t2 = 0.f;
  for (int f = 0; f < 16; ++f) {
    s1 += u[f] * a1[f];      t1 += v[f] * a1[f];
    s2 += u[f] * a1[16 + f]; t2 += v[f] * a1[16 + f];
  }
  if (tid < NN) {
    const int i = tid;
    const float f1i = xls[i] * s1 + t1;
    float m = -1e30f;
    for (int j = 0; j < NN; ++j)
      if (adjm[i * 129 + j] != 0.f)
        m = fmaxf(m, lrelu(f1i + xls[j] * s2 + t2));
    float ssum = 0.f, ps = 0.f;
    for (int j = 0; j < NN; ++j)
      if (adjm[i * 129 + j] != 0.f) {
        const float wgt = expf(lrelu(f1i + xls[j] * s2 + t2) - m);
        ssum += wgt; ps += wgt * xls[j];
      }
    p[i] = ps / ssum;
  }
  __syncthreads();
  if (tid < NN) {
    const int i = tid;
    float xg1[16];
#pragma unroll
    for (int f = 0; f < 16; ++f) {
      const float ov = p[i] * u[f] + v[f];
      xg1[f] = ov > 0.f ? ov : expm1f(ov);   // elu
    }
    float wrow[8];
#pragma unroll
    for (int f2 = 0; f2 < 8; ++f2) wrow[f2] = 0.f;
#pragma unroll
    for (int f = 0; f < 16; ++f) {
      const float xv = xg1[f];
#pragma unroll
      for (int f2 = 0; f2 < 8; ++f2) wrow[f2] += xv * W2[f * 8 + f2];
    }
    float fb1 = 0.f, fb2 = 0.f;
#pragma unroll
    for (int f2 = 0; f2 < 8; ++f2) {
      Wh2[i][f2] = wrow[f2];
      fb1 += wrow[f2] * a2[f2];
      fb2 += wrow[f2] * a2[8 + f2];
    }
    f1b[i] = fb1; f2b[i] = fb2;
  }
  __syncthreads();
  if (tid < NN) {
    const int i = tid;
    const float fi = f1b[i];
    float m = -1e30f;
    for (int j = 0; j < NN; ++j)
      if (adjm[i * 129 + j] != 0.f)
        m = fmaxf(m, lrelu(fi + f2b[j]));
    float ssum = 0.f;
    float o[8];
#pragma unroll
    for (int f2 = 0; f2 < 8; ++f2) o[f2] = 0.f;
    for (int j = 0; j < NN; ++j)
      if (adjm[i * 129 + j] != 0.f) {
        const float wgt = expf(lrelu(fi + f2b[j]) - m);
        ssum += wgt;
#pragma unroll
        for (int f2 = 0; f2 < 8; ++f2) o[f2] += wgt * Wh2[j][f2];
      }
    const float inv = 1.f / ssum;
#pragma unroll
    for (int f2 = 0; f2 < 8; ++f2)
      xg_out[b * (NN * 8) + i * 8 + f2] = o[f2] * inv;
  }
}

// ---------------------------------------------------------------------------
// Kernel D: the three MLP heads on c = [xl(64) | xg(1024)]  -> out[16]
// ---------------------------------------------------------------------------
__global__ __launch_bounds__(384) void heads_kernel(
    const float* __restrict__ xl, const float* __restrict__ xg,
    const float* __restrict__ dw1, const float* __restrict__ db1,
    const float* __restrict__ dw2, const float* __restrict__ db2,
    const float* __restrict__ rw1, const float* __restrict__ rb1,
    const float* __restrict__ rw2, const float* __restrict__ rb2,
    const float* __restrict__ vw1, const float* __restrict__ vb1,
    const float* __restrict__ vw2, const float* __restrict__ vb2,
    float* __restrict__ out)
{
  __shared__ float c[BATCH][1088];
  __shared__ float hid[12][32];
  const int tid = threadIdx.x;
  for (int idx = tid; idx < BATCH * 1088; idx += 384) {
    const int bb = idx / 1088, k = idx - bb * 1088;
    c[bb][k] = (k < 64) ? xl[bb * 64 + k] : xg[bb * 1024 + (k - 64)];
  }
  __syncthreads();
  const int bh = tid >> 5;          // 0..11 = b*3 + head
  const int h = tid & 31;
  const int b = bh / 3, head = bh - 3 * b;
  const float* w1 = (head == 0) ? dw1 : (head == 1) ? rw1 : vw1;
  const float* b1 = (head == 0) ? db1 : (head == 1) ? rb1 : vb1;
  float acc = b1[h];
  for (int k = 0; k < 1088; ++k) acc += c[b][k] * w1[k * 32 + h];
  hid[bh][h] = fmaxf(acc, 0.f);
  __syncthreads();
  if (tid < 16) {
    int head2, b2, o, odim;
    if (tid < 4)      { head2 = 0; b2 = tid;            o = 0;              odim = 1; }
    else if (tid < 8) { head2 = 1; b2 = tid - 4;        o = 0;              odim = 1; }
    else              { head2 = 2; b2 = (tid - 8) >> 1; o = (tid - 8) & 1;  odim = 2; }
    const float* w2  = (head2 == 0) ? dw2 : (head2 == 1) ? rw2 : vw2;
    const float* b2p = (head2 == 0) ? db2 : (head2 == 1) ? rb2 : vb2;
    float acc2 = b2p[o];
    for (int hh = 0; hh < 32; ++hh) acc2 += hid[b2 * 3 + head2][hh] * w2[hh * odim + o];
    out[tid] = acc2;   // [dir(4) | ret(4) | vol(8)] flat in return order
  }
}

// ---------------------------------------------------------------------------
extern "C" void kernel_launch(void* const* d_in, const int* in_sizes, int n_in,
                              void* d_out, int out_size, void* d_ws, size_t ws_size,
                              hipStream_t stream) {
  const float* x     = (const float*)d_in[0];
  const int*   adj   = (const int*)  d_in[1];
  const float* emb_w = (const float*)d_in[2];
  const float* emb_b = (const float*)d_in[3];
  const float* g1W   = (const float*)d_in[4];
  const float* g1a   = (const float*)d_in[5];
  const float* g2W   = (const float*)d_in[6];
  const float* g2a   = (const float*)d_in[7];
  const float* Wih0  = (const float*)d_in[8];
  const float* Whh0  = (const float*)d_in[9];
  const float* bih0  = (const float*)d_in[10];
  const float* bhh0  = (const float*)d_in[11];
  const float* Wih1  = (const float*)d_in[12];
  const float* Whh1  = (const float*)d_in[13];
  const float* bih1  = (const float*)d_in[14];
  const float* bhh1  = (const float*)d_in[15];
  const float* dw1 = (const float*)d_in[16]; const float* db1 = (const float*)d_in[17];
  const float* dw2 = (const float*)d_in[18]; const float* db2 = (const float*)d_in[19];
  const float* rw1 = (const float*)d_in[20]; const float* rb1 = (const float*)d_in[21];
  const float* rw2 = (const float*)d_in[22]; const float* rb2 = (const float*)d_in[23];
  const float* vw1 = (const float*)d_in[24]; const float* vb1 = (const float*)d_in[25];
  const float* vw2 = (const float*)d_in[26]; const float* vb2 = (const float*)d_in[27];

  float* ws = (float*)d_ws;
  float* X0 = ws;                         // SEQ*BATCH*256 floats = 2 MB
  float* xl = ws + SEQ * BATCH * G4;      // 256 floats
  float* xg = xl + BATCH * HID;           // 4096 floats
  float* out = (float*)d_out;

  hipLaunchKernelGGL(x0_gemm, dim3(128), dim3(256), 0, stream,
                     x, Wih0, bih0, bhh0, X0);
  hipLaunchKernelGGL(gat_kernel, dim3(BATCH), dim3(256), 0, stream,
                     x, adj, emb_w, emb_b, g1W, g1a, g2W, g2a, xg);
  hipLaunchKernelGGL(lstm_scan, dim3(BATCH), dim3(512), 0, stream,
                     X0, Whh0, Wih1, Whh1, bih1, bhh1, xl);
  hipLaunchKernelGGL(heads_kernel, dim3(1), dim3(384), 0, stream,
                     xl, xg, dw1, db1, dw2, db2, rw1, rb1, rw2, rb2,
                     vw1, vb1, vw2, vb2, out);
}

// Round 2
// 620.731 us; speedup vs baseline: 1.2172x; 1.2172x over previous
//
#include <hip/hip_runtime.h>

#define SEQ   512
#define BATCH 4
#define NN    128
#define HID   64
#define G4    256   // 4*HID gates per layer

// Fast activations: v_exp_f32 + v_rcp_f32 (abs err ~1e-6, threshold is 1e-3)
__device__ __forceinline__ float frcp(float x)  { return __builtin_amdgcn_rcpf(x); }
__device__ __forceinline__ float fsigm(float x) { return frcp(1.f + __expf(-x)); }
__device__ __forceinline__ float ftanh(float x) { return 1.f - 2.f * frcp(1.f + __expf(2.f * x)); }
__device__ __forceinline__ float lrelu(float x) { return x > 0.f ? x : 0.2f * x; }
__device__ __forceinline__ float dot4f(float4 w, float4 h) {
  return fmaf(w.x, h.x, fmaf(w.y, h.y, fmaf(w.z, h.z, w.w * h.w)));
}

// ---------------------------------------------------------------------------
// prep_kernel: blocks [0,128) = X0 input-GEMM for LSTM layer 0;
//              blocks [128,132) = GAT for the 4 last-timestep graphs.
// X0 part: 512 threads = 256 gates x 2 half-dots (64 weights/thread ->
// guaranteed VGPR-resident), lane pair combined via __shfl_xor(p,1).
// ---------------------------------------------------------------------------
__global__ __launch_bounds__(512) void prep_kernel(
    const float* __restrict__ x, const float* __restrict__ Wih0,
    const float* __restrict__ bih0, const float* __restrict__ bhh0,
    float* __restrict__ X0,
    const int* __restrict__ adj, const float* __restrict__ emb_w,
    const float* __restrict__ emb_b,
    const float* __restrict__ W1, const float* __restrict__ a1,
    const float* __restrict__ W2, const float* __restrict__ a2,
    float* __restrict__ xg_out)
{
  const int tid = threadIdx.x;
  if (blockIdx.x < 128) {
    // ---------------- X0 GEMM ----------------
    __shared__ __align__(16) float xls[NN];
    const int g = tid >> 1, half = tid & 1;
    float4 w4[16];
    {
      const float4* wp = reinterpret_cast<const float4*>(Wih0 + g * NN + half * 64);
#pragma unroll
      for (int i = 0; i < 16; ++i) w4[i] = wp[i];
    }
    const float bsum = bih0[g] + bhh0[g];
    const int r0 = blockIdx.x * 16;
    for (int r = r0; r < r0 + 16; ++r) {
      const int tt = r >> 2, b = r & 3;
      if (tid < NN) xls[tid] = x[(b * SEQ + tt) * NN + tid];
      __syncthreads();
      const float4* hp = reinterpret_cast<const float4*>(&xls[half * 64]);
      float p0 = 0.f, p1 = 0.f, p2 = 0.f, p3 = 0.f;
#pragma unroll
      for (int k = 0; k < 16; k += 4) {
        p0 += dot4f(w4[k],     hp[k]);
        p1 += dot4f(w4[k + 1], hp[k + 1]);
        p2 += dot4f(w4[k + 2], hp[k + 2]);
        p3 += dot4f(w4[k + 3], hp[k + 3]);
      }
      float p = (p0 + p1) + (p2 + p3);
      p += __shfl_xor(p, 1);
      if (half == 0) X0[r * G4 + g] = p + bsum;
      __syncthreads();
    }
    return;
  }
  // ---------------- GAT (rank-1 GAT1 + explicit GAT2) ----------------
  const int b = blockIdx.x - 128;
  __shared__ float adjm[NN * 129];
  __shared__ __align__(16) float xls[NN];
  __shared__ float u[16], v[16];
  __shared__ float Wh2[NN][9];
  __shared__ float f1b[NN], f2b[NN];
  __shared__ float p[NN];

  for (int idx = tid; idx < NN * NN; idx += 512)
    adjm[(idx >> 7) * 129 + (idx & 127)] = (adj[idx] > 0) ? 1.f : 0.f;
  if (tid < NN) xls[tid] = x[(b * SEQ + (SEQ - 1)) * NN + tid];
  if (tid < 16) {
    float uu = 0.f, vv = 0.f;
    for (int fp = 0; fp < 16; ++fp) {
      uu += emb_w[fp] * W1[fp * 16 + tid];
      vv += emb_b[fp] * W1[fp * 16 + tid];
    }
    u[tid] = uu; v[tid] = vv;
  }
  __syncthreads();
  float s1 = 0.f, t1 = 0.f, s2 = 0.f, t2 = 0.f;
  for (int f = 0; f < 16; ++f) {
    s1 += u[f] * a1[f];      t1 += v[f] * a1[f];
    s2 += u[f] * a1[16 + f]; t2 += v[f] * a1[16 + f];
  }
  if (tid < NN) {
    const int i = tid;
    const float f1i = xls[i] * s1 + t1;
    float m = -1e30f;
    for (int j = 0; j < NN; ++j)
      if (adjm[i * 129 + j] != 0.f)
        m = fmaxf(m, lrelu(f1i + xls[j] * s2 + t2));
    float ssum = 0.f, ps = 0.f;
    for (int j = 0; j < NN; ++j)
      if (adjm[i * 129 + j] != 0.f) {
        const float wgt = __expf(lrelu(f1i + xls[j] * s2 + t2) - m);
        ssum += wgt; ps += wgt * xls[j];
      }
    p[i] = ps / ssum;
  }
  __syncthreads();
  if (tid < NN) {
    const int i = tid;
    float xg1[16];
#pragma unroll
    for (int f = 0; f < 16; ++f) {
      const float ov = p[i] * u[f] + v[f];
      xg1[f] = ov > 0.f ? ov : expm1f(ov);   // elu
    }
    float wrow[8];
#pragma unroll
    for (int f2 = 0; f2 < 8; ++f2) wrow[f2] = 0.f;
#pragma unroll
    for (int f = 0; f < 16; ++f) {
      const float xv = xg1[f];
#pragma unroll
      for (int f2 = 0; f2 < 8; ++f2) wrow[f2] += xv * W2[f * 8 + f2];
    }
    float fb1 = 0.f, fb2 = 0.f;
#pragma unroll
    for (int f2 = 0; f2 < 8; ++f2) {
      Wh2[i][f2] = wrow[f2];
      fb1 += wrow[f2] * a2[f2];
      fb2 += wrow[f2] * a2[8 + f2];
    }
    f1b[i] = fb1; f2b[i] = fb2;
  }
  __syncthreads();
  if (tid < NN) {
    const int i = tid;
    const float fi = f1b[i];
    float m = -1e30f;
    for (int j = 0; j < NN; ++j)
      if (adjm[i * 129 + j] != 0.f)
        m = fmaxf(m, lrelu(fi + f2b[j]));
    float ssum = 0.f;
    float o[8];
#pragma unroll
    for (int f2 = 0; f2 < 8; ++f2) o[f2] = 0.f;
    for (int j = 0; j < NN; ++j)
      if (adjm[i * 129 + j] != 0.f) {
        const float wgt = __expf(lrelu(fi + f2b[j]) - m);
        ssum += wgt;
#pragma unroll
        for (int f2 = 0; f2 < 8; ++f2) o[f2] += wgt * Wh2[j][f2];
      }
    const float inv = 1.f / ssum;
#pragma unroll
    for (int f2 = 0; f2 < 8; ++f2)
      xg_out[b * (NN * 8) + i * 8 + f2] = o[f2] * inv;
  }
}

// ---------------------------------------------------------------------------
// lstm_heads: fused 2-layer LSTM scan (skewed pipeline) + MLP heads.
// 768 threads: [0,256) layer0 gates (64-wt dot); [256,768) layer1 gates
// split into two 64-wt half-dots (lane^32 partner, __shfl_xor reduce).
// Every thread holds exactly 16 float4 of weights -> VGPR-resident.
// Cell state tracked redundantly by all waves (unit = idx&63); single
// writer wave per layer. 2 barriers/step.
// ---------------------------------------------------------------------------
__global__ __launch_bounds__(768, 3) void lstm_heads(
    const float* __restrict__ X0, const float* __restrict__ Whh0,
    const float* __restrict__ Wih1, const float* __restrict__ Whh1,
    const float* __restrict__ bih1, const float* __restrict__ bhh1,
    const float* __restrict__ xg,
    const float* __restrict__ dw1, const float* __restrict__ db1,
    const float* __restrict__ dw2, const float* __restrict__ db2,
    const float* __restrict__ rw1, const float* __restrict__ rb1,
    const float* __restrict__ rw2, const float* __restrict__ rb2,
    const float* __restrict__ vw1, const float* __restrict__ vb1,
    const float* __restrict__ vw2, const float* __restrict__ vb2,
    float* __restrict__ out)
{
  const int b = blockIdx.x;
  const int tid = threadIdx.x;
  const bool grp1 = (tid >= 256);
  __shared__ __align__(16) float h0s[HID];
  __shared__ __align__(16) float h1s[HID];
  __shared__ float gact[2][G4];
  __shared__ float cbuf[1088];
  __shared__ float hidc[3][32];

  int gate, type;
  const float* wrow;
  const float* hsrc;
  float bsum = 0.f;
  if (!grp1) {
    gate = tid;                       // 0..255
    type = gate >> 6;
    wrow = Whh0 + gate * HID;
    hsrc = h0s;
  } else {
    const int idx = tid - 256;        // 0..511
    const int wv = idx >> 6, lane = idx & 63;
    gate = wv * 32 + (lane & 31);     // 0..255
    type = gate >> 6;                 // wave-uniform
    const int half = lane >> 5;       // 0: Wih1*h0, 1: Whh1*h1
    wrow = (half ? Whh1 : Wih1) + gate * HID;
    hsrc = half ? h1s : h0s;
    bsum = bih1[gate] + bhh1[gate];
  }
  float4 w4[16];
  {
    const float4* wp = reinterpret_cast<const float4*>(wrow);
#pragma unroll
    for (int i = 0; i < 16; ++i) w4[i] = wp[i];
  }
  const int u = (grp1 ? (tid - 256) : tid) & 63;   // unit for redundant combine
  float cst = 0.f;
  float cur = 0.f, nxt = 0.f;
  if (!grp1) cur = X0[b * G4 + tid];
  if (tid < HID) h0s[tid] = 0.f;
  else if (tid >= 64 && tid < 128) h1s[tid - 64] = 0.f;
  __syncthreads();

  for (int tt = 0; tt <= SEQ; ++tt) {
    const bool act0 = (!grp1) && (tt < SEQ);
    const bool act1 = grp1 && (tt >= 1);
    if (act0) {   // prefetch next X0 early (independent of the dot)
      const int nt = (tt + 1 < SEQ) ? (tt + 1) : (SEQ - 1);
      nxt = X0[(nt * BATCH + b) * G4 + tid];
    }
    if (act0 || act1) {
      const float4* hp = reinterpret_cast<const float4*>(hsrc);
      float p0 = 0.f, p1 = 0.f, p2 = 0.f, p3 = 0.f;
#pragma unroll
      for (int k = 0; k < 16; k += 4) {
        p0 += dot4f(w4[k],     hp[k]);
        p1 += dot4f(w4[k + 1], hp[k + 1]);
        p2 += dot4f(w4[k + 2], hp[k + 2]);
        p3 += dot4f(w4[k + 3], hp[k + 3]);
      }
      float p = (p0 + p1) + (p2 + p3);
      if (!grp1) {
        const float a = p + cur;
        gact[0][gate] = (type == 2) ? ftanh(a) : fsigm(a);
      } else {
        p += __shfl_xor(p, 32);       // combine the two half-dots
        if (((tid - 256) & 63) < 32) {
          const float a = p + bsum;
          gact[1][gate] = (type == 2) ? ftanh(a) : fsigm(a);
        }
      }
    }
    __syncthreads();
    if (act0 || act1) {
      const int layer = grp1 ? 1 : 0;
      const float i_ = gact[layer][u];
      const float f_ = gact[layer][64 + u];
      const float gg = gact[layer][128 + u];
      const float o_ = gact[layer][192 + u];
      cst = fmaf(f_, cst, i_ * gg);
      const float h = o_ * ftanh(cst);
      if (!grp1) { if (tid < 64) h0s[u] = h; }          // wave 0 writes
      else       { if (tid < 320) h1s[u] = h; }         // wave 4 writes
    }
    if (!grp1) cur = nxt;
    __syncthreads();
  }

  // ---------------- fused heads: c = [h1(64) | xg_b(1024)] ----------------
  for (int k = tid; k < 1088; k += 768)
    cbuf[k] = (k < 64) ? h1s[k] : xg[b * 1024 + (k - 64)];
  __syncthreads();
  if (tid < 96) {
    const int head = tid >> 5, h = tid & 31;
    const float* w1 = (head == 0) ? dw1 : (head == 1) ? rw1 : vw1;
    const float* b1 = (head == 0) ? db1 : (head == 1) ? rb1 : vb1;
    float a0 = 0.f, a1v = 0.f, a2v = 0.f, a3v = 0.f;
    for (int k = 0; k < 1088; k += 4) {
      a0  = fmaf(cbuf[k],     w1[k * 32 + h],       a0);
      a1v = fmaf(cbuf[k + 1], w1[(k + 1) * 32 + h], a1v);
      a2v = fmaf(cbuf[k + 2], w1[(k + 2) * 32 + h], a2v);
      a3v = fmaf(cbuf[k + 3], w1[(k + 3) * 32 + h], a3v);
    }
    hidc[head][h] = fmaxf(b1[h] + ((a0 + a1v) + (a2v + a3v)), 0.f);
  }
  __syncthreads();
  if (tid < 4) {
    const int head2 = (tid < 2) ? tid : 2;
    const int o = (tid < 2) ? 0 : (tid - 2);
    const int odim = (tid < 2) ? 1 : 2;
    const float* w2  = (head2 == 0) ? dw2 : (head2 == 1) ? rw2 : vw2;
    const float* b2p = (head2 == 0) ? db2 : (head2 == 1) ? rb2 : vb2;
    float acc = b2p[o];
    for (int hh = 0; hh < 32; ++hh)
      acc = fmaf(hidc[head2][hh], w2[hh * odim + o], acc);
    const int off = (tid == 0) ? b : (tid == 1) ? (4 + b) : (8 + 2 * b + o);
    out[off] = acc;   // [dir(4) | ret(4) | vol(4x2)] flat
  }
}

// ---------------------------------------------------------------------------
extern "C" void kernel_launch(void* const* d_in, const int* in_sizes, int n_in,
                              void* d_out, int out_size, void* d_ws, size_t ws_size,
                              hipStream_t stream) {
  const float* x     = (const float*)d_in[0];
  const int*   adj   = (const int*)  d_in[1];
  const float* emb_w = (const float*)d_in[2];
  const float* emb_b = (const float*)d_in[3];
  const float* g1W   = (const float*)d_in[4];
  const float* g1a   = (const float*)d_in[5];
  const float* g2W   = (const float*)d_in[6];
  const float* g2a   = (const float*)d_in[7];
  const float* Wih0  = (const float*)d_in[8];
  const float* Whh0  = (const float*)d_in[9];
  const float* bih0  = (const float*)d_in[10];
  const float* bhh0  = (const float*)d_in[11];
  const float* Wih1  = (const float*)d_in[12];
  const float* Whh1  = (const float*)d_in[13];
  const float* bih1  = (const float*)d_in[14];
  const float* bhh1  = (const float*)d_in[15];
  const float* dw1 = (const float*)d_in[16]; const float* db1 = (const float*)d_in[17];
  const float* dw2 = (const float*)d_in[18]; const float* db2 = (const float*)d_in[19];
  const float* rw1 = (const float*)d_in[20]; const float* rb1 = (const float*)d_in[21];
  const float* rw2 = (const float*)d_in[22]; const float* rb2 = (const float*)d_in[23];
  const float* vw1 = (const float*)d_in[24]; const float* vb1 = (const float*)d_in[25];
  const float* vw2 = (const float*)d_in[26]; const float* vb2 = (const float*)d_in[27];

  float* ws = (float*)d_ws;
  float* X0 = ws;                         // SEQ*BATCH*256 floats = 2 MB
  float* xg = ws + SEQ * BATCH * G4;      // 4096 floats
  float* out = (float*)d_out;

  hipLaunchKernelGGL(prep_kernel, dim3(132), dim3(512), 0, stream,
                     x, Wih0, bih0, bhh0, X0,
                     adj, emb_w, emb_b, g1W, g1a, g2W, g2a, xg);
  hipLaunchKernelGGL(lstm_heads, dim3(BATCH), dim3(768), 0, stream,
                     X0, Whh0, Wih1, Whh1, bih1, bhh1, xg,
                     dw1, db1, dw2, db2, rw1, rb1, rw2, rb2,
                     vw1, vb1, vw2, vb2, out);
}